// Round 3
// baseline (322.861 us; speedup 1.0000x reference)
//
#include <hip/hip_runtime.h>
#include <hip/hip_bf16.h>

// Problem: N=32, W=64, H=64, C=256, D_STYLE=256. All fp32 in/out.
// out = leaky0.1( (inputs .* ca .* pa) @ Wconv )
// Pipeline (4 kernels):
//   K1 style->q, zero colsum/Ssum
//   K2 stream inputs: colsum atomics, pa_logits, Ssum=sum(exp(logit)) atomics, bf16 copy
//   K3 ca softmax + fold ca into per-batch bf16 weights (transposed)
//   K4 bf16 MFMA GEMM (m97-style global_load_lds staging), pa=exp(logit)/S + leaky in epilogue

#define NBATCH 32
#define PIX 4096          // 64*64
#define CH 256
#define SCALE 0.0625f     // 1/sqrt(256)

typedef __attribute__((ext_vector_type(8))) short short8;
typedef __attribute__((ext_vector_type(4))) short short4v;
typedef __attribute__((ext_vector_type(4))) float floatx4;

typedef __attribute__((address_space(3))) unsigned lds_u32;
typedef const __attribute__((address_space(1))) unsigned gbl_u32;

__device__ __forceinline__ short f2bf(float x) {
    unsigned u = __builtin_bit_cast(unsigned, x);
    u += 0x7fffu + ((u >> 16) & 1u);   // round-to-nearest-even
    return (short)(u >> 16);
}

// ---------------- K1: q = leaky_relu(style @ w_dense, 0.3); zero colsum/Ssum -
__global__ __launch_bounds__(256) void style_kernel(
    const float* __restrict__ style, const float* __restrict__ wd,
    float* __restrict__ q, float* __restrict__ colsum, float* __restrict__ Ssum)
{
    __shared__ float s[256];
    const int n = blockIdx.x, t = threadIdx.x;
    s[t] = style[n * 256 + t];
    __syncthreads();
    float acc = 0.f;
#pragma unroll 8
    for (int k = 0; k < 256; ++k) acc += s[k] * wd[k * 256 + t];
    q[n * 256 + t] = acc > 0.f ? acc : 0.3f * acc;
    colsum[n * 256 + t] = 0.f;
    if (t == 0) Ssum[n] = 0.f;
}

// -- K2: colsum += sum_p in; pa_logits = in.q*s; Ssum += exp(logit); bf16 copy
__global__ __launch_bounds__(256) void reduce_convert_kernel(
    const float* __restrict__ inp, const float* __restrict__ q,
    float* __restrict__ colsum, float* __restrict__ pa_logits,
    float* __restrict__ Ssum, short* __restrict__ in_bf)
{
    __shared__ float sm[4][256];
    const int n = blockIdx.y;
    const int chunk = blockIdx.x;        // 32 chunks of 128 pixels
    const int lane = threadIdx.x & 63, w = threadIdx.x >> 6;
    const float4 qv = *(const float4*)&q[n * 256 + lane * 4];
    float4 cs = make_float4(0.f, 0.f, 0.f, 0.f);
    const int pbase = chunk * 128 + w * 32;
    const float* base = inp + ((size_t)n * PIX + pbase) * CH;
    short* bfb = in_bf + ((size_t)n * PIX + pbase) * CH;
    float es = 0.f;
    for (int j = 0; j < 32; ++j) {
        float4 v = *(const float4*)&base[(size_t)j * CH + lane * 4];
        short4v s;
        s.x = f2bf(v.x); s.y = f2bf(v.y); s.z = f2bf(v.z); s.w = f2bf(v.w);
        *(short4v*)&bfb[(size_t)j * CH + lane * 4] = s;
        float d = v.x * qv.x + v.y * qv.y + v.z * qv.z + v.w * qv.w;
        cs.x += v.x; cs.y += v.y; cs.z += v.z; cs.w += v.w;
#pragma unroll
        for (int off = 32; off; off >>= 1) d += __shfl_xor(d, off);
        if (lane == 0) {
            const float lg = d * SCALE;
            pa_logits[n * PIX + pbase + j] = lg;
            es += __expf(lg);
        }
    }
    if (lane == 0) atomicAdd(&Ssum[n], es);
    *(float4*)&sm[w][lane * 4] = cs;
    __syncthreads();
    const int t = threadIdx.x;
    float tot = sm[0][t] + sm[1][t] + sm[2][t] + sm[3][t];
    atomicAdd(&colsum[n * 256 + t], tot);
}

// --- K3: ca = softmax_c(colsum*q*s); wn[n][co][ci] = bf16(wc[ci][co]*ca[ci]) -
// grid (8 co-tiles, 32 batches); ca recomputed per block (cheap).
__global__ __launch_bounds__(256) void ca_fold_kernel(
    const float* __restrict__ colsum, const float* __restrict__ q,
    const float* __restrict__ wc, short* __restrict__ wn)
{
    __shared__ float red[256];
    __shared__ float cas[256];
    __shared__ float tile[32][33];
    const int n = blockIdx.y, t = threadIdx.x;

    float lg = colsum[n * 256 + t] * q[n * 256 + t] * SCALE;
    red[t] = lg; __syncthreads();
    for (int s = 128; s > 0; s >>= 1) {
        if (t < s) red[t] = fmaxf(red[t], red[t + s]);
        __syncthreads();
    }
    float m = red[0]; __syncthreads();
    float e = __expf(lg - m);
    red[t] = e; __syncthreads();
    for (int s = 128; s > 0; s >>= 1) {
        if (t < s) red[t] += red[t + s];
        __syncthreads();
    }
    cas[t] = e / red[0];
    __syncthreads();

    const int co0 = blockIdx.x * 32;
    const int tx = t & 31, ty = t >> 5;  // 32 x 8
    short* wout = wn + (size_t)n * 65536;
    for (int cit = 0; cit < 8; ++cit) {
        const int ci0 = cit * 32;
        if (cit) __syncthreads();
#pragma unroll
        for (int r = 0; r < 4; ++r)
            tile[ty + r * 8][tx] = wc[(ci0 + ty + r * 8) * 256 + co0 + tx];
        __syncthreads();
        const float cav = cas[ci0 + tx];
#pragma unroll
        for (int r = 0; r < 4; ++r)
            wout[(co0 + ty + r * 8) * 256 + ci0 + tx] = f2bf(tile[tx][ty + r * 8] * cav);
    }
}

// -------- K4: y = leaky0.1( (in_bf @ wn^T) .* exp(logit)/S ) via bf16 MFMA ---
// 128x128 tile, BK=64, 4 waves (2x2), each wave 64x64 = 4x4 MFMA 16x16x32.
// m97 staging: unpadded [128][64] LDS, global_load_lds width=16.
__global__ __launch_bounds__(256) void conv_mfma(
    const short* __restrict__ in_bf, const float* __restrict__ pa_logits,
    const float* __restrict__ Ssum, const short* __restrict__ wn,
    float* __restrict__ out)
{
    __shared__ __attribute__((aligned(16))) short As[128 * 64];
    __shared__ __attribute__((aligned(16))) short Bs[128 * 64];

    const int n   = blockIdx.z;
    const int m0  = blockIdx.y * 128;   // pixel base
    const int co0 = blockIdx.x * 128;   // output-channel base
    const int tid = threadIdx.x;
    const int lane = tid & 63, wid = tid >> 6;
    const int wm = wid & 1, wn_ = wid >> 1;
    const int l16 = lane & 15, quad = lane >> 4;
    const int lr = lane >> 3, lc = lane & 7;  // staging: row-in-8, 16B chunk

    floatx4 acc[4][4] = {};

    const short* Ab = in_bf + ((size_t)(n * PIX + m0)) * CH;
    const short* Bb = wn + (size_t)n * 65536 + (size_t)co0 * CH;

    for (int kb = 0; kb < 4; ++kb) {
        const int k0 = kb * 64;
        if (kb) __syncthreads();
        // each wave stages rows [32*wid, 32*wid+32) of A and B: 4 chunks x 1KB
#pragma unroll
        for (int c = 0; c < 4; ++c) {
            const int r = 32 * wid + 8 * c + lr;
            __builtin_amdgcn_global_load_lds(
                (gbl_u32*)(Ab + (size_t)r * CH + k0 + lc * 8),
                (lds_u32*)(&As[(32 * wid + 8 * c) * 64]), 16, 0, 0);
            __builtin_amdgcn_global_load_lds(
                (gbl_u32*)(Bb + (size_t)r * CH + k0 + lc * 8),
                (lds_u32*)(&Bs[(32 * wid + 8 * c) * 64]), 16, 0, 0);
        }
        __syncthreads();
#pragma unroll
        for (int kk = 0; kk < 64; kk += 32) {
            short8 af[4], bfr[4];
#pragma unroll
            for (int mt = 0; mt < 4; ++mt)
                af[mt] = *(const short8*)&As[(wm * 64 + mt * 16 + l16) * 64 + kk + quad * 8];
#pragma unroll
            for (int nt = 0; nt < 4; ++nt)
                bfr[nt] = *(const short8*)&Bs[(wn_ * 64 + nt * 16 + l16) * 64 + kk + quad * 8];
#pragma unroll
            for (int mt = 0; mt < 4; ++mt)
#pragma unroll
                for (int nt = 0; nt < 4; ++nt)
                    acc[mt][nt] = __builtin_amdgcn_mfma_f32_16x16x32_bf16(
                        af[mt], bfr[nt], acc[mt][nt], 0, 0, 0);
        }
    }

    // epilogue: z = acc * exp(logit)*invS; leaky 0.1; store
    const float invS = 1.0f / Ssum[n];
#pragma unroll
    for (int mt = 0; mt < 4; ++mt) {
#pragma unroll
        for (int reg = 0; reg < 4; ++reg) {
            const int pix = m0 + wm * 64 + mt * 16 + quad * 4 + reg;
            const float pav = __expf(pa_logits[n * PIX + pix]) * invS;
            float* orow = out + ((size_t)(n * PIX + pix)) * CH + co0 + wn_ * 64;
#pragma unroll
            for (int nt = 0; nt < 4; ++nt) {
                float z = acc[mt][nt][reg] * pav;
                orow[nt * 16 + l16] = z > 0.f ? z : 0.1f * z;
            }
        }
    }
}

extern "C" void kernel_launch(void* const* d_in, const int* in_sizes, int n_in,
                              void* d_out, int out_size, void* d_ws, size_t ws_size,
                              hipStream_t stream) {
    const float* inputs = (const float*)d_in[0];   // [32,64,64,256]
    const float* style  = (const float*)d_in[1];   // [32,256]
    const float* wdense = (const float*)d_in[2];   // [256,256]
    const float* wconv  = (const float*)d_in[3];   // [1,1,256,256] = [ci][co]
    float* out = (float*)d_out;

    // workspace layout (bytes), all 16B-aligned
    char* ws = (char*)d_ws;
    float* q         = (float*)(ws + 0);          // 32 KB
    float* colsum    = (float*)(ws + 32768);      // 32 KB
    float* Ssum      = (float*)(ws + 65536);      // 128 B (padded to 4 KB)
    float* pa_logits = (float*)(ws + 69632);      // 512 KB
    short* wn        = (short*)(ws + 593920);     // 4 MB
    short* in_bf     = (short*)(ws + 4788224);    // 64 MB

    style_kernel<<<NBATCH, 256, 0, stream>>>(style, wdense, q, colsum, Ssum);
    reduce_convert_kernel<<<dim3(32, NBATCH), 256, 0, stream>>>(
        inputs, q, colsum, pa_logits, Ssum, in_bf);
    ca_fold_kernel<<<dim3(8, NBATCH), 256, 0, stream>>>(colsum, q, wconv, wn);
    conv_mfma<<<dim3(2, 32, NBATCH), 256, 0, stream>>>(in_bf, pa_logits, Ssum, wn, out);
}